// Round 5
// baseline (7541.465 us; speedup 1.0000x reference)
//
#include <hip/hip_runtime.h>
#include <cstddef>
#include <cstdint>

// CubicRNN MI355X — round 5: 256-thread blocks (Ng=2 x Kg=2) with 56 KB LDS for
// 2-block/CU co-residency; anti-diagonal cell fusion (independent cells in one
// launch); fast transcendentals; MFMA y-conv. K-loop numerics = round 4
// (split-f16 activations x single-f16 weights, absmax 3.7e-9 verified).

typedef __attribute__((ext_vector_type(8))) _Float16 f16x8;
typedef __attribute__((ext_vector_type(4))) float f32x4;
typedef unsigned short u16;

#define HW 4096
#define NB 4

__device__ __forceinline__ float sigm(float x){
  return __fdividef(1.f, 1.f + __expf(-x));
}
__device__ __forceinline__ float tanh_fast(float x){
  return 1.f - __fdividef(2.f, 1.f + __expf(2.f*x));
}
__device__ __forceinline__ u16 f2h(float x){
  union { _Float16 f; u16 u; } c; c.f = (_Float16)x; return c.u;
}
__device__ __forceinline__ float h2f(u16 h){
  union { _Float16 f; u16 u; } c; c.u = h; return (float)c.f;
}

__global__ __launch_bounds__(256) void zero4(uint4* __restrict__ p, size_t n){
  size_t i = (size_t)blockIdx.x*blockDim.x + threadIdx.x;
  size_t st = (size_t)gridDim.x*blockDim.x;
  uint4 z = make_uint4(0u,0u,0u,0u);
  for (; i < n; i += st) p[i] = z;
}

// Pack conv weights (fp32 OIHW) -> [unit=tap*3+kc][co(128)][k(32)] f16,
// cat channels remapped to uniform 96 (layer0: ci0->slot0, ci1..64->slot32..95).
__global__ __launch_bounds__(256) void pack_w(const float* __restrict__ src,
    u16* __restrict__ dst, int taps, int cin, int l0){
  int idx = blockIdx.x*256 + threadIdx.x;
  int k = idx & 31, co = (idx>>5) & 127, rest = idx >> 12;
  int tap = rest/3, kc = rest - tap*3;
  int p = kc*32 + k;
  int ci = l0 ? ((p==0) ? 0 : ((p>=32) ? p-31 : -1)) : p;
  float wv = 0.f;
  if (ci >= 0 && ci < cin) wv = src[((size_t)co*cin + ci)*taps + tap];
  dst[idx] = f2h(wv);
}

// Pack y-conv weights [co 32][cin 64] fp32 -> [ku 2][co 32][k 32] f16.
__global__ __launch_bounds__(256) void pack_wy(const float* __restrict__ src,
    u16* __restrict__ dst){
  int idx = blockIdx.x*256 + threadIdx.x;   // 2048
  int k = idx & 31, co = (idx>>5) & 31, ku = idx >> 10;
  dst[idx] = f2h(src[co*64 + ku*32 + k]);
}

// cat layout: [b][chunk 0..23][pixel 0..4095][elem 0..7] f16
// chunk = half*12 + (slot>>3); elem = slot&7; half0=hi, half1=lo.
__device__ __forceinline__ void put_pair(u16* base, int b, int slot, int pix, float v){
  _Float16 h = (_Float16)v;
  float lof = v - (float)h;
  size_t o = ((size_t)(b*24 + (slot>>3))*4096 + pix)*8 + (slot&7);
  base[o] = f2h(v);
  base[o + (size_t)393216] = f2h(lof);     // +12 chunks
}

__global__ __launch_bounds__(256) void frame_fill(const float* __restrict__ inseq,
    const float* __restrict__ predbuf, int step,
    u16* __restrict__ c0, u16* __restrict__ c1, u16* __restrict__ c2){
  int s = blockIdx.y;
  u16* dst = (s==0) ? c0 : ((s==1) ? c1 : c2);
  int i = blockIdx.x*256 + threadIdx.x;    // b*4096 + px
  int b = i >> 12, px = i & 4095;
  int j = step + s;
  float v = (j < 10) ? inseq[((size_t)b*10 + j)*HW + px]
                     : predbuf[(size_t)(j-3)*(NB*HW) + (size_t)b*HW + px];
  put_pair(dst, b, 0, px, v);
}

struct CellArgs {
  const u16* cat_in;
  const u16* wz; const u16* wx;            // packed conv weights f16
  const float *bx, *bz;                    // [128]
  const float* cx_src; float* cx_dst;      // fp32 c-state (dst may be null)
  float* cz;                               // in-place
  u16 *hx0, *hx1, *hz, *y_dst;             // cat dst (null = skip)
  const u16* wyp;                          // packed y weights (null = no y-conv)
  const float* by;                         // [32]
  const float* wl;                         // [32]; non-null = pred mode
  float* pred_out;
  float* final_out;                        // d_out + ti*4096 (b-stride 40960)
};
struct MultiArgs { CellArgs c[3]; };

// LDS: halo 24 chunks x 145 u4 = 55680 B. Overlays (valid after K-loop):
//   exch  f32 [0, 16384)
//   hb16  u16 [16384, 33024)   16 rows x 65 u4 (rows = half*8 + ch_octet)
//   ybufF f32 [33024, 41216)   [64 px][32 co]
#define LDS_BYTES 55808

__global__ __launch_bounds__(256, 2) void cell_kernel(MultiArgs ma){
  __shared__ __align__(16) char smem[LDS_BYTES];
  uint4* AU4   = (uint4*)smem;
  float* exchF = (float*)smem;
  f32x4* exchV = (f32x4*)smem;
  u16*   HB    = (u16*)(smem + 16384);
  float* ybufF = (float*)(smem + 33024);

  CellArgs a = ma.c[blockIdx.z];
  const int tid = threadIdx.x;
  const int b = blockIdx.y;
  const int reg = blockIdx.x;
  const int R0 = (reg >> 3) << 3, C0 = (reg & 7) << 3;   // 8x8 pixel region

  // ---- stage 12x12 halo, 24 chunk-planes, coalesced ----
  for (int i = tid; i < 3456; i += 256) {
    int px = i % 144, cp = i / 144;
    int hr = px / 12, hc = px - hr*12;
    int gy = R0 + hr - 2, gx = C0 + hc - 2;
    uint4 v = make_uint4(0u,0u,0u,0u);
    if (gy >= 0 && gy < 64 && gx >= 0 && gx < 64)
      v = *reinterpret_cast<const uint4*>(a.cat_in + ((size_t)(b*24 + cp)*4096 + gy*64 + gx)*8);
    AU4[cp*145 + px] = v;
  }
  __syncthreads();

  // ---- K-loop: Ng=2 (64 co/wave) x Kg=2 ----
  const int wave = tid >> 6, lane = tid & 63;
  const int n = wave & 1, kg = wave >> 1;
  const int q = lane >> 4, n16 = lane & 15;
  const int row_in = n16 >> 3, col = n16 & 7;
  const int wlo = (n*64 + n16)*32 + q*8;

  f32x4 zf = {0.f,0.f,0.f,0.f};
  f32x4 accz[4][4], accx[4][4];            // [nf][m]
#pragma unroll
  for (int nf = 0; nf < 4; ++nf)
#pragma unroll
    for (int m = 0; m < 4; ++m) { accz[nf][m] = zf; accx[nf][m] = zf; }

  f16x8 Bz[4];
#pragma unroll
  for (int nf = 0; nf < 4; ++nf)
    Bz[nf] = *(const f16x8*)(a.wz + (size_t)kg*4096 + wlo + nf*512);

#pragma unroll 1
  for (int u = kg; u < 75; u += 2) {
    int tap = u/3, kc = u - tap*3;
    int ky = tap/5, kx = tap - ky*5;
    bool inner = ((unsigned)(ky-1) <= 2u) && ((unsigned)(kx-1) <= 2u);

    f16x8 Bx[4];
    if (inner) {
      int xu = ((ky-1)*3 + (kx-1))*3 + kc;
#pragma unroll
      for (int nf = 0; nf < 4; ++nf)
        Bx[nf] = *(const f16x8*)(a.wx + (size_t)xu*4096 + wlo + nf*512);
    }

    int ai0 = (kc*4 + q)*145 + (row_in + ky)*12 + col + kx;
    f16x8 Ah[4], Al[4];
#pragma unroll
    for (int m = 0; m < 4; ++m) {
      Ah[m] = *(const f16x8*)(AU4 + ai0 + m*24);
      Al[m] = *(const f16x8*)(AU4 + 1740 + ai0 + m*24);
    }

#pragma unroll
    for (int nf = 0; nf < 4; ++nf)
#pragma unroll
      for (int m = 0; m < 4; ++m)
        accz[nf][m] = __builtin_amdgcn_mfma_f32_16x16x32_f16(Ah[m], Bz[nf], accz[nf][m], 0,0,0);

    int un = (u + 2 < 75) ? u + 2 : kg;    // depth-1 z-prefetch
    f16x8 Bzn[4];
#pragma unroll
    for (int nf = 0; nf < 4; ++nf)
      Bzn[nf] = *(const f16x8*)(a.wz + (size_t)un*4096 + wlo + nf*512);

#pragma unroll
    for (int nf = 0; nf < 4; ++nf)
#pragma unroll
      for (int m = 0; m < 4; ++m)
        accz[nf][m] = __builtin_amdgcn_mfma_f32_16x16x32_f16(Al[m], Bz[nf], accz[nf][m], 0,0,0);

    if (inner) {
#pragma unroll
      for (int nf = 0; nf < 4; ++nf)
#pragma unroll
        for (int m = 0; m < 4; ++m) {
          accx[nf][m] = __builtin_amdgcn_mfma_f32_16x16x32_f16(Ah[m], Bx[nf], accx[nf][m], 0,0,0);
          accx[nf][m] = __builtin_amdgcn_mfma_f32_16x16x32_f16(Al[m], Bx[nf], accx[nf][m], 0,0,0);
        }
    }
#pragma unroll
    for (int nf = 0; nf < 4; ++nf) Bz[nf] = Bzn[nf];
  }

  // ---- 8 reduce+gate passes: (cv 2) x (m 4), exch 16 KB each ----
  bool first = true;
  for (int cv = 0; cv < 2; ++cv) {                 // 0 = z, 1 = x
#pragma unroll 1
    for (int m = 0; m < 4; ++m) {
      __syncthreads();                             // exch free
#pragma unroll
      for (int nf = 0; nf < 4; ++nf)
        exchV[((kg*2 + n)*4 + nf)*64 + lane] = cv ? accx[nf][m] : accz[nf][m];
      if (first && a.wyp) {                        // init ybuf with bias (halo dead now)
#pragma unroll
        for (int i = 0; i < 8; ++i) { int e = tid + 256*i; ybufF[e] = a.by[e & 31]; }
      }
      first = false;
      __syncthreads();
      const float* bias = cv ? a.bx : a.bz;
#pragma unroll
      for (int it = 0; it < 2; ++it) {
        int e = tid + 256*it;
        int ch = e & 31, p16 = e >> 5;
        int q_ = p16 >> 2, r_ = p16 & 3;
        float gate[4];
#pragma unroll
        for (int g = 0; g < 4; ++g) {
          int co = g*32 + ch;
          int n_ = co >> 6, nf_ = (co >> 4) & 3, nl = co & 15;
          int base = ((n_*4 + nf_)*64 + q_*16 + nl)*4 + r_;
          gate[g] = exchF[base] + exchF[base + 2048] + bias[co];
        }
        int px = (2*m + (p16 >> 3))*8 + (p16 & 7);
        int pxg = (R0 + (px >> 3))*64 + C0 + (px & 7);
        size_t pix = (size_t)b*4096 + pxg;
        float ig = gate[0], fg = gate[1], gg = gate[2], og = gate[3];
        float h;
        if (cv == 0) {
          float c = a.cz[pix*32 + ch];
          float cn = sigm(fg + 0.01f)*c + sigm(ig)*tanh_fast(gg);
          h = sigm(og)*tanh_fast(cn);
          a.cz[pix*32 + ch] = cn;
          if (a.hz) put_pair(a.hz, b, 64 + ch, pxg, h);
        } else {
          float c = a.cx_src[pix*32 + ch];
          float cn = sigm(fg + 0.01f)*c + sigm(ig)*tanh_fast(gg);
          h = sigm(og)*tanh_fast(cn);
          if (a.cx_dst) a.cx_dst[pix*32 + ch] = cn;
          if (a.hx0) put_pair(a.hx0, b, 32 + ch, pxg, h);
          if (a.hx1) put_pair(a.hx1, b, 32 + ch, pxg, h);
        }
        // h pairs -> LDS A-layout for y-conv: c64 = x?ch : 32+ch
        int c64 = (cv == 0) ? 32 + ch : ch;
        u16 hh = f2h(h);
        float hlo = h - h2f(hh);
        int u4i = ((c64 >> 3))*65 + px;            // hi rows 0..7
        HB[u4i*8 + (c64 & 7)] = hh;
        HB[(u4i + 8*65)*8 + (c64 & 7)] = f2h(hlo); // lo rows 8..15
      }
    }
  }
  __syncthreads();

  // ---- MFMA y-conv (64 -> 32) + ds_add reduce ----
  if (a.wyp) {
    int ku = wave & 1, nfy = wave >> 1;            // 4 waves: ku x nfy
    f16x8 By = *(const f16x8*)(a.wyp + ((ku*32 + nfy*16 + n16)*32 + q*8));
#pragma unroll
    for (int m = 0; m < 4; ++m) {
      f16x8 Ahh = *(const f16x8*)(HB + ((ku*4 + q)*65 + m*16 + n16)*8);
      f16x8 All = *(const f16x8*)(HB + ((8 + ku*4 + q)*65 + m*16 + n16)*8);
      f32x4 acc = __builtin_amdgcn_mfma_f32_16x16x32_f16(All, By, zf, 0,0,0);
      acc = __builtin_amdgcn_mfma_f32_16x16x32_f16(Ahh, By, acc, 0,0,0);
#pragma unroll
      for (int r = 0; r < 4; ++r)
        atomicAdd(&ybufF[(m*16 + q*4 + r)*32 + nfy*16 + n16], acc[r]);
    }
    __syncthreads();
#pragma unroll
    for (int i = 0; i < 8; ++i) {
      int e = tid + 256*i;
      int co = e & 31, px = e >> 5;
      int pxg = (R0 + (px >> 3))*64 + C0 + (px & 7);
      float y = ybufF[e];
      if (a.y_dst) put_pair(a.y_dst, b, co, pxg, y);
    }
    if (a.wl && tid < 64) {
      int px = tid;
      int pxg = (R0 + (px >> 3))*64 + C0 + (px & 7);
      float p = 0.f;
#pragma unroll
      for (int c2 = 0; c2 < 32; ++c2) p += a.wl[c2] * ybufF[px*32 + c2];
      a.pred_out[(size_t)b*4096 + pxg] = p;
      if (a.final_out) a.final_out[(size_t)b*40960 + pxg] = p;
    }
  }
}

extern "C" void kernel_launch(void* const* d_in, const int* in_sizes, int n_in,
                              void* d_out, int out_size, void* d_ws, size_t ws_size,
                              hipStream_t stream)
{
  const float* input_seq = (const float*)d_in[0];
  const float* w_x0 = (const float*)d_in[1];
  const float* b_x0 = (const float*)d_in[2];
  const float* w_z0 = (const float*)d_in[3];
  const float* b_z0 = (const float*)d_in[4];
  const float* w_y0 = (const float*)d_in[5];
  const float* b_y0 = (const float*)d_in[6];
  const float* w_x1 = (const float*)d_in[7];
  const float* b_x1 = (const float*)d_in[8];
  const float* w_z1 = (const float*)d_in[9];
  const float* b_z1 = (const float*)d_in[10];
  const float* w_y1 = (const float*)d_in[11];
  const float* b_y1 = (const float*)d_in[12];
  const float* w_last = (const float*)d_in[13];
  (void)in_sizes; (void)n_in; (void)out_size; (void)ws_size;

  uint8_t* wsb = (uint8_t*)d_ws;
  size_t off = 0;
  auto alloc = [&](size_t bytes) -> void* {
    void* p = wsb + off; off += (bytes + 255) & ~(size_t)255; return p;
  };

  const size_t CATB = (size_t)NB*24*4096*8*2;    // 6,291,456 B
  u16* cat[3][3][2];
  for (int l = 0; l < 3; ++l)
    for (int s = 0; s < 3; ++s) {
      cat[l][s][0] = (u16*)alloc(CATB);
      cat[l][s][1] = (s == 0) ? (u16*)alloc(CATB) : cat[l][s][0];
    }
  const size_t CB = (size_t)NB*HW*32*4;
  float* cx[3][2]; float* cz[3];
  for (int l = 0; l < 3; ++l) { cx[l][0] = (float*)alloc(CB); cx[l][1] = (float*)alloc(CB); }
  for (int l = 0; l < 3; ++l) cz[l] = (float*)alloc(CB);
  size_t zero_bytes = off;

  u16 *wzb[9], *wxb[9], *wyb[9];
  for (int c = 0; c < 9; ++c) {
    wzb[c] = (u16*)alloc(75*4096*2);
    wxb[c] = (u16*)alloc(27*4096*2);
    wyb[c] = (u16*)alloc(2048*2);
  }
  float* predbuf = (float*)alloc((size_t)18*NB*HW*4);

  zero4<<<2048, 256, 0, stream>>>((uint4*)wsb, zero_bytes/16);

  for (int l = 0; l < 3; ++l)
    for (int s = 0; s < 3; ++s) {
      int cell = l*3 + s;
      const float *srcx, *srcz; int cin;
      if (l == 0) { srcx = w_x0 + (size_t)s*128*65*9;  srcz = w_z0 + (size_t)s*128*65*25;  cin = 65; }
      else { int li = (l-1)*3 + s;
             srcx = w_x1 + (size_t)li*128*96*9; srcz = w_z1 + (size_t)li*128*96*25; cin = 96; }
      pack_w<<<(75*4096)/256, 256, 0, stream>>>(srcz, wzb[cell], 25, cin, l==0);
      pack_w<<<(27*4096)/256, 256, 0, stream>>>(srcx, wxb[cell], 9, cin, l==0);
      const float* wy = nullptr;
      if (l == 0) wy = w_y0 + (size_t)s*32*64;
      else if (l == 1) wy = w_y1 + (size_t)s*32*64;
      else if (s == 2) wy = w_y1 + (size_t)5*32*64;
      if (wy) pack_wy<<<8, 256, 0, stream>>>(wy, wyb[cell]);
    }

  static const int diag[5][3][2] = {
    {{0,0},{0,0},{0,0}}, {{0,1},{1,0},{0,0}}, {{0,2},{1,1},{2,0}},
    {{1,2},{2,1},{0,0}}, {{2,2},{0,0},{0,0}} };
  static const int diagN[5] = {1,2,3,2,1};

  for (int step = 0; step < 18; ++step) {
    int par = step & 1, npar = par ^ 1;
    frame_fill<<<dim3(64,3), 256, 0, stream>>>(input_seq, predbuf, step,
        cat[0][0][par], cat[0][1][0], cat[0][2][0]);
    for (int d = 0; d < 5; ++d) {
      MultiArgs ma;
      for (int i = 0; i < diagN[d]; ++i) {
        int l = diag[d][i][0], s = diag[d][i][1];
        int cell = l*3 + s;
        CellArgs A;
        A.cat_in = cat[l][s][(s==0) ? par : 0];
        A.wz = wzb[cell]; A.wx = wxb[cell];
        if (l == 0) { A.bx = b_x0 + s*128; A.bz = b_z0 + s*128; }
        else { int li = (l-1)*3 + s; A.bx = b_x1 + li*128; A.bz = b_z1 + li*128; }
        A.cx_src = (s == 2) ? cx[l][1] : cx[l][0];
        A.cx_dst = (s == 0) ? cx[l][0] : ((s == 1) ? cx[l][1] : nullptr);
        A.cz = cz[l];
        A.hx0 = (s == 0) ? cat[l][1][0] : ((s == 1) ? cat[l][2][0] : nullptr);
        A.hx1 = (s == 0) ? cat[l][0][npar] : nullptr;
        A.hz  = (s < 2) ? cat[l][s+1][0] : cat[l][0][npar];
        A.wyp = nullptr; A.by = nullptr; A.y_dst = nullptr;
        A.wl = nullptr; A.pred_out = nullptr; A.final_out = nullptr;
        if (l < 2) {
          A.wyp = wyb[cell];
          A.by = (l == 0) ? (b_y0 + s*32) : (b_y1 + s*32);
          A.y_dst = cat[l+1][s][(s==0) ? par : 0];
        } else if (s == 2) {
          A.wyp = wyb[cell]; A.by = b_y1 + 5*32;
          A.wl = w_last;
          A.pred_out = predbuf + (size_t)step*NB*HW;
          A.final_out = (step >= 8) ? ((float*)d_out + (size_t)(step-8)*HW) : nullptr;
        }
        ma.c[i] = A;
      }
      for (int i = diagN[d]; i < 3; ++i) ma.c[i] = ma.c[0];
      cell_kernel<<<dim3(64, NB, diagN[d]), 256, 0, stream>>>(ma);
    }
  }
}

// Round 6
// 6738.132 us; speedup vs baseline: 1.1192x; 1.1192x over previous
//
#include <hip/hip_runtime.h>
#include <cstddef>
#include <cstdint>

// CubicRNN MI355X — round 6: round-5 structure + coalesced uint4 writeback of
// h/y pairs from LDS (kills the scattered-u16 write-allocate amplification that
// made round 5 HBM-bound: WRITE_SIZE 192 MB/dispatch -> ~30 MB predicted).
// K-loop numerics: split-f16 activations x single-f16 weights (absmax 3.7e-9).

typedef __attribute__((ext_vector_type(8))) _Float16 f16x8;
typedef __attribute__((ext_vector_type(4))) float f32x4;
typedef unsigned short u16;

#define HW 4096
#define NB 4

__device__ __forceinline__ float sigm(float x){
  return __fdividef(1.f, 1.f + __expf(-x));
}
__device__ __forceinline__ float tanh_fast(float x){
  return 1.f - __fdividef(2.f, 1.f + __expf(2.f*x));
}
__device__ __forceinline__ u16 f2h(float x){
  union { _Float16 f; u16 u; } c; c.f = (_Float16)x; return c.u;
}
__device__ __forceinline__ float h2f(u16 h){
  union { _Float16 f; u16 u; } c; c.u = h; return (float)c.f;
}

__global__ __launch_bounds__(256) void zero4(uint4* __restrict__ p, size_t n){
  size_t i = (size_t)blockIdx.x*blockDim.x + threadIdx.x;
  size_t st = (size_t)gridDim.x*blockDim.x;
  uint4 z = make_uint4(0u,0u,0u,0u);
  for (; i < n; i += st) p[i] = z;
}

// Pack conv weights (fp32 OIHW) -> [unit=tap*3+kc][co(128)][k(32)] f16,
// cat channels remapped to uniform 96 (layer0: ci0->slot0, ci1..64->slot32..95).
__global__ __launch_bounds__(256) void pack_w(const float* __restrict__ src,
    u16* __restrict__ dst, int taps, int cin, int l0){
  int idx = blockIdx.x*256 + threadIdx.x;
  int k = idx & 31, co = (idx>>5) & 127, rest = idx >> 12;
  int tap = rest/3, kc = rest - tap*3;
  int p = kc*32 + k;
  int ci = l0 ? ((p==0) ? 0 : ((p>=32) ? p-31 : -1)) : p;
  float wv = 0.f;
  if (ci >= 0 && ci < cin) wv = src[((size_t)co*cin + ci)*taps + tap];
  dst[idx] = f2h(wv);
}

// Pack y-conv weights [co 32][cin 64] fp32 -> [ku 2][co 32][k 32] f16.
__global__ __launch_bounds__(256) void pack_wy(const float* __restrict__ src,
    u16* __restrict__ dst){
  int idx = blockIdx.x*256 + threadIdx.x;   // 2048
  int k = idx & 31, co = (idx>>5) & 31, ku = idx >> 10;
  dst[idx] = f2h(src[co*64 + ku*32 + k]);
}

// cat layout: [b][chunk 0..23][pixel 0..4095][elem 0..7] f16
// chunk = half*12 + (slot>>3); elem = slot&7; half0=hi, half1=lo.
__device__ __forceinline__ void put_pair(u16* base, int b, int slot, int pix, float v){
  _Float16 h = (_Float16)v;
  float lof = v - (float)h;
  size_t o = ((size_t)(b*24 + (slot>>3))*4096 + pix)*8 + (slot&7);
  base[o] = f2h(v);
  base[o + (size_t)393216] = f2h(lof);     // +12 chunks
}

__global__ __launch_bounds__(256) void frame_fill(const float* __restrict__ inseq,
    const float* __restrict__ predbuf, int step,
    u16* __restrict__ c0, u16* __restrict__ c1, u16* __restrict__ c2){
  int s = blockIdx.y;
  u16* dst = (s==0) ? c0 : ((s==1) ? c1 : c2);
  int i = blockIdx.x*256 + threadIdx.x;    // b*4096 + px
  int b = i >> 12, px = i & 4095;
  int j = step + s;
  float v = (j < 10) ? inseq[((size_t)b*10 + j)*HW + px]
                     : predbuf[(size_t)(j-3)*(NB*HW) + (size_t)b*HW + px];
  put_pair(dst, b, 0, px, v);
}

struct CellArgs {
  const u16* cat_in;
  const u16* wz; const u16* wx;            // packed conv weights f16
  const float *bx, *bz;                    // [128]
  const float* cx_src; float* cx_dst;      // fp32 c-state (dst may be null)
  float* cz;                               // in-place
  u16 *hx0, *hx1, *hz, *y_dst;             // cat dst (null = skip)
  const u16* wyp;                          // packed y weights (null = no y-conv)
  const float* by;                         // [32]
  const float* wl;                         // [32]; non-null = pred mode
  float* pred_out;
  float* final_out;                        // d_out + ti*4096 (b-stride 40960)
};
struct MultiArgs { CellArgs c[3]; };

// LDS: halo 24 chunks x 145 u4 = 55680 B. Overlays (valid after K-loop):
//   exch f32 [0, 16384)
//   HB   u16 [16384, 33024)  16 rows x 65 u4  (row = half*8 + c64_octet, c64 = x?ch : 32+ch)
//   YB   u16 [33024, 41344)   8 rows x 65 u4  (row = half*4 + co_octet)
#define LDS_BYTES 55808

__global__ __launch_bounds__(256, 2) void cell_kernel(MultiArgs ma){
  __shared__ __align__(16) char smem[LDS_BYTES];
  uint4* AU4   = (uint4*)smem;
  float* exchF = (float*)smem;
  f32x4* exchV = (f32x4*)smem;
  u16*   HB    = (u16*)(smem + 16384);
  uint4* HBu4  = (uint4*)(smem + 16384);
  u16*   YB    = (u16*)(smem + 33024);
  uint4* YBu4  = (uint4*)(smem + 33024);

  CellArgs a = ma.c[blockIdx.z];
  const int tid = threadIdx.x;
  const int b = blockIdx.y;
  const int reg = blockIdx.x;
  const int R0 = (reg >> 3) << 3, C0 = (reg & 7) << 3;   // 8x8 pixel region

  // ---- stage 12x12 halo, 24 chunk-planes, coalesced ----
  for (int i = tid; i < 3456; i += 256) {
    int px = i % 144, cp = i / 144;
    int hr = px / 12, hc = px - hr*12;
    int gy = R0 + hr - 2, gx = C0 + hc - 2;
    uint4 v = make_uint4(0u,0u,0u,0u);
    if (gy >= 0 && gy < 64 && gx >= 0 && gx < 64)
      v = *reinterpret_cast<const uint4*>(a.cat_in + ((size_t)(b*24 + cp)*4096 + gy*64 + gx)*8);
    AU4[cp*145 + px] = v;
  }
  __syncthreads();

  // ---- K-loop: Ng=2 (64 co/wave) x Kg=2 ----
  const int wave = tid >> 6, lane = tid & 63;
  const int n = wave & 1, kg = wave >> 1;
  const int q = lane >> 4, n16 = lane & 15;
  const int row_in = n16 >> 3, col = n16 & 7;
  const int wlo = (n*64 + n16)*32 + q*8;

  f32x4 zf = {0.f,0.f,0.f,0.f};
  f32x4 accz[4][4], accx[4][4];            // [nf][m]
#pragma unroll
  for (int nf = 0; nf < 4; ++nf)
#pragma unroll
    for (int m = 0; m < 4; ++m) { accz[nf][m] = zf; accx[nf][m] = zf; }

  f16x8 Bz[4];
#pragma unroll
  for (int nf = 0; nf < 4; ++nf)
    Bz[nf] = *(const f16x8*)(a.wz + (size_t)kg*4096 + wlo + nf*512);

#pragma unroll 1
  for (int u = kg; u < 75; u += 2) {
    int tap = u/3, kc = u - tap*3;
    int ky = tap/5, kx = tap - ky*5;
    bool inner = ((unsigned)(ky-1) <= 2u) && ((unsigned)(kx-1) <= 2u);

    f16x8 Bx[4];
    if (inner) {
      int xu = ((ky-1)*3 + (kx-1))*3 + kc;
#pragma unroll
      for (int nf = 0; nf < 4; ++nf)
        Bx[nf] = *(const f16x8*)(a.wx + (size_t)xu*4096 + wlo + nf*512);
    }

    int ai0 = (kc*4 + q)*145 + (row_in + ky)*12 + col + kx;
    f16x8 Ah[4], Al[4];
#pragma unroll
    for (int m = 0; m < 4; ++m) {
      Ah[m] = *(const f16x8*)(AU4 + ai0 + m*24);
      Al[m] = *(const f16x8*)(AU4 + 1740 + ai0 + m*24);
    }

#pragma unroll
    for (int nf = 0; nf < 4; ++nf)
#pragma unroll
      for (int m = 0; m < 4; ++m)
        accz[nf][m] = __builtin_amdgcn_mfma_f32_16x16x32_f16(Ah[m], Bz[nf], accz[nf][m], 0,0,0);

    int un = (u + 2 < 75) ? u + 2 : kg;    // depth-1 z-prefetch
    f16x8 Bzn[4];
#pragma unroll
    for (int nf = 0; nf < 4; ++nf)
      Bzn[nf] = *(const f16x8*)(a.wz + (size_t)un*4096 + wlo + nf*512);

#pragma unroll
    for (int nf = 0; nf < 4; ++nf)
#pragma unroll
      for (int m = 0; m < 4; ++m)
        accz[nf][m] = __builtin_amdgcn_mfma_f32_16x16x32_f16(Al[m], Bz[nf], accz[nf][m], 0,0,0);

    if (inner) {
#pragma unroll
      for (int nf = 0; nf < 4; ++nf)
#pragma unroll
        for (int m = 0; m < 4; ++m) {
          accx[nf][m] = __builtin_amdgcn_mfma_f32_16x16x32_f16(Ah[m], Bx[nf], accx[nf][m], 0,0,0);
          accx[nf][m] = __builtin_amdgcn_mfma_f32_16x16x32_f16(Al[m], Bx[nf], accx[nf][m], 0,0,0);
        }
    }
#pragma unroll
    for (int nf = 0; nf < 4; ++nf) Bz[nf] = Bzn[nf];
  }

  // ---- 8 reduce+gate passes: (cv 2) x (m 4); h pairs -> LDS HB only ----
  for (int cv = 0; cv < 2; ++cv) {                 // 0 = z, 1 = x
#pragma unroll 1
    for (int m = 0; m < 4; ++m) {
      __syncthreads();                             // exch free
#pragma unroll
      for (int nf = 0; nf < 4; ++nf)
        exchV[((kg*2 + n)*4 + nf)*64 + lane] = cv ? accx[nf][m] : accz[nf][m];
      __syncthreads();
      const float* bias = cv ? a.bx : a.bz;
#pragma unroll
      for (int it = 0; it < 2; ++it) {
        int e = tid + 256*it;
        int ch = e & 31, p16 = e >> 5;
        int q_ = p16 >> 2, r_ = p16 & 3;
        float gate[4];
#pragma unroll
        for (int g = 0; g < 4; ++g) {
          int co = g*32 + ch;
          int n_ = co >> 6, nf_ = (co >> 4) & 3, nl = co & 15;
          int base = ((n_*4 + nf_)*64 + q_*16 + nl)*4 + r_;
          gate[g] = exchF[base] + exchF[base + 2048] + bias[co];
        }
        int px = (2*m + (p16 >> 3))*8 + (p16 & 7);
        int pxg = (R0 + (px >> 3))*64 + C0 + (px & 7);
        size_t pix = (size_t)b*4096 + pxg;
        float ig = gate[0], fg = gate[1], gg = gate[2], og = gate[3];
        float h;
        if (cv == 0) {
          float c = a.cz[pix*32 + ch];
          float cn = sigm(fg + 0.01f)*c + sigm(ig)*tanh_fast(gg);
          h = sigm(og)*tanh_fast(cn);
          a.cz[pix*32 + ch] = cn;
        } else {
          float c = a.cx_src[pix*32 + ch];
          float cn = sigm(fg + 0.01f)*c + sigm(ig)*tanh_fast(gg);
          h = sigm(og)*tanh_fast(cn);
          if (a.cx_dst) a.cx_dst[pix*32 + ch] = cn;
        }
        int c64 = (cv == 0) ? 32 + ch : ch;
        u16 hh = f2h(h);
        float hlo = h - h2f(hh);
        int u4i = (c64 >> 3)*65 + px;              // hi rows 0..7
        HB[u4i*8 + (c64 & 7)] = hh;
        HB[(u4i + 8*65)*8 + (c64 & 7)] = f2h(hlo); // lo rows 8..15
      }
    }
  }
  __syncthreads();                                 // HB complete

  // ---- coalesced h writeback: uint4 bursts (128-B fully-dirty lines) ----
  {
    int u4row = tid >> 6, px = tid & 63;           // oct 0..3, px 0..63
    int pxg = (R0 + (px >> 3))*64 + C0 + (px & 7);
    size_t gbase = (size_t)b*24*4096 + pxg;
    // x-half: HB hi rows 0..3 / lo rows 8..11 -> chunks 4..7 / 16..19
    uint4 vh = HBu4[u4row*65 + px];
    uint4 vl = HBu4[(8 + u4row)*65 + px];
    if (a.hx0) {
      *(uint4*)(a.hx0 + (gbase + (size_t)(4 + u4row)*4096)*8)  = vh;
      *(uint4*)(a.hx0 + (gbase + (size_t)(16 + u4row)*4096)*8) = vl;
    }
    if (a.hx1) {
      *(uint4*)(a.hx1 + (gbase + (size_t)(4 + u4row)*4096)*8)  = vh;
      *(uint4*)(a.hx1 + (gbase + (size_t)(16 + u4row)*4096)*8) = vl;
    }
    // z-half: HB hi rows 4..7 / lo rows 12..15 -> chunks 8..11 / 20..23
    uint4 wh = HBu4[(4 + u4row)*65 + px];
    uint4 wl4 = HBu4[(12 + u4row)*65 + px];
    if (a.hz) {
      *(uint4*)(a.hz + (gbase + (size_t)(8 + u4row)*4096)*8)  = wh;
      *(uint4*)(a.hz + (gbase + (size_t)(20 + u4row)*4096)*8) = wl4;
    }
  }

  // ---- MFMA y-conv (64 -> 32): 4 waves = (nfy x mpair), ku in-wave ----
  if (a.wyp) {
    int nfy = wave & 1, mp = wave >> 1;
    f32x4 acc[2] = {zf, zf};
#pragma unroll
    for (int ku = 0; ku < 2; ++ku) {
      f16x8 By = *(const f16x8*)(a.wyp + ((ku*32 + nfy*16 + n16)*32 + q*8));
#pragma unroll
      for (int ml = 0; ml < 2; ++ml) {
        int m = mp*2 + ml;
        f16x8 Ahh = *(const f16x8*)(HB + ((ku*4 + q)*65 + m*16 + n16)*8);
        f16x8 All = *(const f16x8*)(HB + ((8 + ku*4 + q)*65 + m*16 + n16)*8);
        acc[ml] = __builtin_amdgcn_mfma_f32_16x16x32_f16(All, By, acc[ml], 0,0,0);
        acc[ml] = __builtin_amdgcn_mfma_f32_16x16x32_f16(Ahh, By, acc[ml], 0,0,0);
      }
    }
    int co = nfy*16 + n16, oct = co >> 3, el = co & 7;
#pragma unroll
    for (int ml = 0; ml < 2; ++ml) {
      int m = mp*2 + ml;
#pragma unroll
      for (int r = 0; r < 4; ++r) {
        int px = m*16 + q*4 + r;
        float y = acc[ml][r] + a.by[co];
        u16 yh = f2h(y);
        YB[(oct*65 + px)*8 + el] = yh;
        YB[((4 + oct)*65 + px)*8 + el] = f2h(y - h2f(yh));
      }
    }
    __syncthreads();                               // YB complete
    // coalesced y writeback: chunks 0..3 (hi), 12..15 (lo)
    if (a.y_dst) {
      int u4row = tid >> 6, px = tid & 63;
      int pxg = (R0 + (px >> 3))*64 + C0 + (px & 7);
      size_t gbase = (size_t)b*24*4096 + pxg;
      *(uint4*)(a.y_dst + (gbase + (size_t)u4row*4096)*8)        = YBu4[u4row*65 + px];
      *(uint4*)(a.y_dst + (gbase + (size_t)(12 + u4row)*4096)*8) = YBu4[(4 + u4row)*65 + px];
    }
    if (a.wl && tid < 64) {
      int px = tid;
      int pxg = (R0 + (px >> 3))*64 + C0 + (px & 7);
      float p = 0.f;
#pragma unroll
      for (int c2 = 0; c2 < 32; ++c2) {
        int o2 = c2 >> 3, e2 = c2 & 7;
        float y = h2f(YB[(o2*65 + px)*8 + e2]) + h2f(YB[((4 + o2)*65 + px)*8 + e2]);
        p += a.wl[c2] * y;
      }
      a.pred_out[(size_t)b*4096 + pxg] = p;
      if (a.final_out) a.final_out[(size_t)b*40960 + pxg] = p;
    }
  }
}

extern "C" void kernel_launch(void* const* d_in, const int* in_sizes, int n_in,
                              void* d_out, int out_size, void* d_ws, size_t ws_size,
                              hipStream_t stream)
{
  const float* input_seq = (const float*)d_in[0];
  const float* w_x0 = (const float*)d_in[1];
  const float* b_x0 = (const float*)d_in[2];
  const float* w_z0 = (const float*)d_in[3];
  const float* b_z0 = (const float*)d_in[4];
  const float* w_y0 = (const float*)d_in[5];
  const float* b_y0 = (const float*)d_in[6];
  const float* w_x1 = (const float*)d_in[7];
  const float* b_x1 = (const float*)d_in[8];
  const float* w_z1 = (const float*)d_in[9];
  const float* b_z1 = (const float*)d_in[10];
  const float* w_y1 = (const float*)d_in[11];
  const float* b_y1 = (const float*)d_in[12];
  const float* w_last = (const float*)d_in[13];
  (void)in_sizes; (void)n_in; (void)out_size; (void)ws_size;

  uint8_t* wsb = (uint8_t*)d_ws;
  size_t off = 0;
  auto alloc = [&](size_t bytes) -> void* {
    void* p = wsb + off; off += (bytes + 255) & ~(size_t)255; return p;
  };

  const size_t CATB = (size_t)NB*24*4096*8*2;    // 6,291,456 B
  u16* cat[3][3][2];
  for (int l = 0; l < 3; ++l)
    for (int s = 0; s < 3; ++s) {
      cat[l][s][0] = (u16*)alloc(CATB);
      cat[l][s][1] = (s == 0) ? (u16*)alloc(CATB) : cat[l][s][0];
    }
  const size_t CB = (size_t)NB*HW*32*4;
  float* cx[3][2]; float* cz[3];
  for (int l = 0; l < 3; ++l) { cx[l][0] = (float*)alloc(CB); cx[l][1] = (float*)alloc(CB); }
  for (int l = 0; l < 3; ++l) cz[l] = (float*)alloc(CB);
  size_t zero_bytes = off;

  u16 *wzb[9], *wxb[9], *wyb[9];
  for (int c = 0; c < 9; ++c) {
    wzb[c] = (u16*)alloc(75*4096*2);
    wxb[c] = (u16*)alloc(27*4096*2);
    wyb[c] = (u16*)alloc(2048*2);
  }
  float* predbuf = (float*)alloc((size_t)18*NB*HW*4);

  zero4<<<2048, 256, 0, stream>>>((uint4*)wsb, zero_bytes/16);

  for (int l = 0; l < 3; ++l)
    for (int s = 0; s < 3; ++s) {
      int cell = l*3 + s;
      const float *srcx, *srcz; int cin;
      if (l == 0) { srcx = w_x0 + (size_t)s*128*65*9;  srcz = w_z0 + (size_t)s*128*65*25;  cin = 65; }
      else { int li = (l-1)*3 + s;
             srcx = w_x1 + (size_t)li*128*96*9; srcz = w_z1 + (size_t)li*128*96*25; cin = 96; }
      pack_w<<<(75*4096)/256, 256, 0, stream>>>(srcz, wzb[cell], 25, cin, l==0);
      pack_w<<<(27*4096)/256, 256, 0, stream>>>(srcx, wxb[cell], 9, cin, l==0);
      const float* wy = nullptr;
      if (l == 0) wy = w_y0 + (size_t)s*32*64;
      else if (l == 1) wy = w_y1 + (size_t)s*32*64;
      else if (s == 2) wy = w_y1 + (size_t)5*32*64;
      if (wy) pack_wy<<<8, 256, 0, stream>>>(wy, wyb[cell]);
    }

  static const int diag[5][3][2] = {
    {{0,0},{0,0},{0,0}}, {{0,1},{1,0},{0,0}}, {{0,2},{1,1},{2,0}},
    {{1,2},{2,1},{0,0}}, {{2,2},{0,0},{0,0}} };
  static const int diagN[5] = {1,2,3,2,1};

  for (int step = 0; step < 18; ++step) {
    int par = step & 1, npar = par ^ 1;
    frame_fill<<<dim3(64,3), 256, 0, stream>>>(input_seq, predbuf, step,
        cat[0][0][par], cat[0][1][0], cat[0][2][0]);
    for (int d = 0; d < 5; ++d) {
      MultiArgs ma;
      for (int i = 0; i < diagN[d]; ++i) {
        int l = diag[d][i][0], s = diag[d][i][1];
        int cell = l*3 + s;
        CellArgs A;
        A.cat_in = cat[l][s][(s==0) ? par : 0];
        A.wz = wzb[cell]; A.wx = wxb[cell];
        if (l == 0) { A.bx = b_x0 + s*128; A.bz = b_z0 + s*128; }
        else { int li = (l-1)*3 + s; A.bx = b_x1 + li*128; A.bz = b_z1 + li*128; }
        A.cx_src = (s == 2) ? cx[l][1] : cx[l][0];
        A.cx_dst = (s == 0) ? cx[l][0] : ((s == 1) ? cx[l][1] : nullptr);
        A.cz = cz[l];
        A.hx0 = (s == 0) ? cat[l][1][0] : ((s == 1) ? cat[l][2][0] : nullptr);
        A.hx1 = (s == 0) ? cat[l][0][npar] : nullptr;
        A.hz  = (s < 2) ? cat[l][s+1][0] : cat[l][0][npar];
        A.wyp = nullptr; A.by = nullptr; A.y_dst = nullptr;
        A.wl = nullptr; A.pred_out = nullptr; A.final_out = nullptr;
        if (l < 2) {
          A.wyp = wyb[cell];
          A.by = (l == 0) ? (b_y0 + s*32) : (b_y1 + s*32);
          A.y_dst = cat[l+1][s][(s==0) ? par : 0];
        } else if (s == 2) {
          A.wyp = wyb[cell]; A.by = b_y1 + 5*32;
          A.wl = w_last;
          A.pred_out = predbuf + (size_t)step*NB*HW;
          A.final_out = (step >= 8) ? ((float*)d_out + (size_t)(step-8)*HW) : nullptr;
        }
        ma.c[i] = A;
      }
      for (int i = diagN[d]; i < 3; ++i) ma.c[i] = ma.c[0];
      cell_kernel<<<dim3(64, NB, diagN[d]), 256, 0, stream>>>(ma);
    }
  }
}